// Round 2
// baseline (1683.341 us; speedup 1.0000x reference)
//
#include <hip/hip_runtime.h>
#include <hip/hip_bf16.h>
#include <cstdint>
#include <cstddef>

// Problem constants
#define BS   16
#define CIN  256
#define COUT 256
#define HH   80
#define WWW  80
#define HID  16
#define KNUM 5
#define TEMP 30.0f
#define NPIX 6400   // 80*80

// ---------------------------------------------------------------------------
// Kernel 1: global average pool.  x[b][c][80][80] -> pooled[b*256+c]
// ---------------------------------------------------------------------------
__global__ void pool_kernel(const float* __restrict__ x, float* __restrict__ pooled) {
    const int bc = blockIdx.x;                     // b*256 + c
    const float* p = x + (size_t)bc * NPIX;
    float s = 0.f;
    for (int i = threadIdx.x; i < NPIX; i += 256) s += p[i];
    // wave64 reduce
    #pragma unroll
    for (int off = 32; off; off >>= 1) s += __shfl_down(s, off, 64);
    __shared__ float red[4];
    if ((threadIdx.x & 63) == 0) red[threadIdx.x >> 6] = s;
    __syncthreads();
    if (threadIdx.x == 0)
        pooled[bc] = (red[0] + red[1] + red[2] + red[3]) * (1.f / (float)NPIX);
}

// ---------------------------------------------------------------------------
// Kernel 2: attention head (per sample).  Produces:
//   cin_att[b][256], out_att[b][256], agg_b[b][256],
//   coef[b][9][9] where coef[d][s] = k2_att[d] * sum_k n_att[k]*[P_k[d]==s]
// ---------------------------------------------------------------------------
__global__ void attn_kernel(const float* __restrict__ pooled,
                            const float* __restrict__ b_base,
                            const float* __restrict__ b_extra,
                            const float* __restrict__ w_net,
                            const float* __restrict__ w_nfc,
                            const float* __restrict__ w_cin,
                            const float* __restrict__ w_k2,
                            const float* __restrict__ w_out,
                            float* __restrict__ cin_att,
                            float* __restrict__ out_att,
                            float* __restrict__ agg_b,
                            float* __restrict__ coef) {
    const int b = blockIdx.x;
    const int t = threadIdx.x;
    __shared__ float sp[CIN];
    __shared__ float sh[HID];
    __shared__ float sn[KNUM];
    __shared__ float sk2[9];

    sp[t] = pooled[b * CIN + t];
    __syncthreads();

    if (t < HID) {
        float a = 0.f;
        for (int c = 0; c < CIN; ++c) a += sp[c] * w_net[t * CIN + c];
        sh[t] = fmaxf(a, 0.f);
    }
    __syncthreads();

    if (t == 0) {
        float l[KNUM], m = -1e30f;
        for (int k = 0; k < KNUM; ++k) {
            float a = 0.f;
            for (int j = 0; j < HID; ++j) a += sh[j] * w_nfc[k * HID + j];
            l[k] = a / TEMP;
            m = fmaxf(m, l[k]);
        }
        float ssum = 0.f;
        for (int k = 0; k < KNUM; ++k) { l[k] = __expf(l[k] - m); ssum += l[k]; }
        for (int k = 0; k < KNUM; ++k) sn[k] = l[k] / ssum;
    }
    if (t < 9) {
        float a = 0.f;
        for (int j = 0; j < HID; ++j) a += sh[j] * w_k2[t * HID + j];
        sk2[t] = 1.f / (1.f + __expf(-a));
    }
    __syncthreads();

    // per-channel attentions + bias
    {
        float a = 0.f, o = 0.f;
        for (int j = 0; j < HID; ++j) {
            a += sh[j] * w_cin[t * HID + j];
            o += sh[j] * w_out[t * HID + j];
        }
        cin_att[b * CIN + t] = 1.f / (1.f + __expf(-a));
        out_att[b * COUT + t] = 1.f / (1.f + __expf(-o));
        float bb = sn[0] * b_base[t];
        for (int k = 1; k < KNUM; ++k) bb += sn[k] * b_extra[(k - 1) * COUT + t];
        agg_b[b * COUT + t] = bb;
    }

    // coef[d][s]: perm[dest] = source, P_0 = identity
    if (t < 81) {
        const int P45[9]  = {3, 0, 1, 6, 4, 2, 7, 8, 5};
        const int P90[9]  = {6, 3, 0, 7, 4, 1, 8, 5, 2};
        const int P135[9] = {7, 6, 3, 8, 4, 0, 5, 2, 1};
        const int P180[9] = {8, 7, 6, 5, 4, 3, 2, 1, 0};
        const int d = t / 9, s = t % 9;
        float c = 0.f;
        if (d == s)        c += sn[0];
        if (P45[d]  == s)  c += sn[1];
        if (P90[d]  == s)  c += sn[2];
        if (P135[d] == s)  c += sn[3];
        if (P180[d] == s)  c += sn[4];
        coef[b * 81 + t] = c * sk2[d];
    }
}

// ---------------------------------------------------------------------------
// Kernel 3: weight synthesis.
//   wsyn[b][i][tap][o] = out_att[b][o]*cin_att[b][i]* sum_s coef[b][tap][s]*w_base[o][i][s]
// grid = 256 blocks (one per input channel i), 256 threads (o), loop over b.
// ---------------------------------------------------------------------------
__global__ void wsyn_kernel(const float* __restrict__ w_base,
                            const float* __restrict__ cin_att,
                            const float* __restrict__ out_att,
                            const float* __restrict__ coef,
                            float* __restrict__ wsyn) {
    const int i = blockIdx.x;
    const int o = threadIdx.x;
    __shared__ float sc[BS][81];
    __shared__ float sci[BS];
    for (int l = o; l < BS * 81; l += 256) sc[l / 81][l % 81] = coef[l];
    if (o < BS) sci[o] = cin_att[o * CIN + i];
    __syncthreads();

    float wb[9];
    const float* wp = w_base + ((size_t)o * CIN + i) * 9;
    #pragma unroll
    for (int s = 0; s < 9; ++s) wb[s] = wp[s];

    for (int b = 0; b < BS; ++b) {
        const float scale = sci[b] * out_att[b * COUT + o];
        float* outp = wsyn + (((size_t)b * CIN + i) * 9) * COUT + o;
        #pragma unroll
        for (int d = 0; d < 9; ++d) {
            float a = 0.f;
            #pragma unroll
            for (int s = 0; s < 9; ++s) a += sc[b][d * 9 + s] * wb[s];
            outp[(size_t)d * COUT] = a * scale;
        }
    }
}

// ---------------------------------------------------------------------------
// Kernel 4: per-sample 3x3 conv, pad 1.
// Block: 256 threads -> 64 output channels x (16w x 8h) pixels, one sample.
// Per thread: 4 o-channels x 8 pixels register tile.
// Loop over input channels in chunks of 4; x halo + weights staged in LDS.
// __launch_bounds__(256,3): 12 waves/CU (3 blocks/CU) to hide LDS latency;
// VGPR estimate ~110 so the ~170-VGPR cap at 3 waves/EU is safe (no spill).
// ---------------------------------------------------------------------------
__global__ __launch_bounds__(256, 3)
void conv_kernel(const float* __restrict__ x,
                 const float* __restrict__ wsyn,
                 const float* __restrict__ agg_b,
                 float* __restrict__ y) {
    const int tile = blockIdx.x;          // 0..49
    const int tx = tile % 5;              // 16-wide col tile
    const int ty = tile / 5;              // 8-high row tile
    const int oBase = blockIdx.y * 64;
    const int b = blockIdx.z;

    __shared__ float xs[4][10][18];       // 720 floats  (2.9 KB)
    __shared__ float wsh[4][9][64];       // 2304 floats (9.2 KB)

    const int t  = threadIdx.x;
    const int og = t & 15;
    const int oL = og * 4;                // o within tile: 0..60
    const int pg = t >> 4;                // 0..15
    const int r  = pg >> 1;               // row in tile 0..7
    const int c0 = (pg & 1) * 8;          // col half: 0 or 8

    float acc[4][8];
    #pragma unroll
    for (int a = 0; a < 4; ++a)
        #pragma unroll
        for (int p = 0; p < 8; ++p) acc[a][p] = 0.f;

    const int row0 = ty * 8 - 1;
    const int col0 = tx * 16 - 1;
    const float* xb  = x + (size_t)b * CIN * NPIX;
    const float* wsb = wsyn + (size_t)b * CIN * 9 * COUT + oBase;

    for (int icb = 0; icb < CIN / 4; ++icb) {
        // stage x halo patch: 4 ic x 10 rows x 18 cols = 720 floats
        #pragma unroll
        for (int q = 0; q < 3; ++q) {
            const int l = t + q * 256;
            if (l < 720) {
                const int ic  = l / 180;
                const int rem = l % 180;
                const int rr  = rem / 18;
                const int cc  = rem % 18;
                const int gr = row0 + rr, gc = col0 + cc;
                float v = 0.f;
                if ((unsigned)gr < 80u && (unsigned)gc < 80u)
                    v = xb[(size_t)(icb * 4 + ic) * NPIX + gr * 80 + gc];
                ((float*)xs)[l] = v;
            }
        }
        // stage weights: 4 ic x 9 taps x 64 o = 2304 floats (coalesced: o contiguous)
        #pragma unroll
        for (int q = 0; q < 9; ++q) {
            const int l = t + q * 256;
            const int ic  = l / 576;
            const int rem = l % 576;
            const int tap = rem / 64;
            const int o   = rem & 63;
            ((float*)wsh)[l] = wsb[(size_t)(icb * 4 + ic) * 9 * COUT + tap * COUT + o];
        }
        __syncthreads();

        #pragma unroll
        for (int ic = 0; ic < 4; ++ic) {
            float xr[3][10];
            #pragma unroll
            for (int dh = 0; dh < 3; ++dh)
                #pragma unroll
                for (int c = 0; c < 10; ++c) xr[dh][c] = xs[ic][r + dh][c0 + c];
            #pragma unroll
            for (int tap = 0; tap < 9; ++tap) {
                const int dh = tap / 3, dw = tap % 3;
                const float4 wv = *(const float4*)&wsh[ic][tap][oL];
                #pragma unroll
                for (int oo = 0; oo < 4; ++oo) {
                    const float wq = (&wv.x)[oo];
                    #pragma unroll
                    for (int p = 0; p < 8; ++p)
                        acc[oo][p] = fmaf(wq, xr[dh][p + dw], acc[oo][p]);
                }
            }
        }
        __syncthreads();
    }

    // epilogue: add bias, vectorized store
    #pragma unroll
    for (int oo = 0; oo < 4; ++oo) {
        const int o = oBase + oL + oo;
        const float bv = agg_b[b * COUT + o];
        float* yp = y + (size_t)(b * COUT + o) * NPIX + (ty * 8 + r) * 80 + tx * 16 + c0;
        float4 v0 = make_float4(acc[oo][0] + bv, acc[oo][1] + bv,
                                acc[oo][2] + bv, acc[oo][3] + bv);
        float4 v1 = make_float4(acc[oo][4] + bv, acc[oo][5] + bv,
                                acc[oo][6] + bv, acc[oo][7] + bv);
        *(float4*)yp = v0;
        *((float4*)yp + 1) = v1;
    }
}

// ---------------------------------------------------------------------------
extern "C" void kernel_launch(void* const* d_in, const int* in_sizes, int n_in,
                              void* d_out, int out_size, void* d_ws, size_t ws_size,
                              hipStream_t stream) {
    const float* x       = (const float*)d_in[0];
    const float* w_base  = (const float*)d_in[1];
    const float* b_base  = (const float*)d_in[2];
    const float* b_extra = (const float*)d_in[3];
    const float* w_net   = (const float*)d_in[4];
    const float* w_nfc   = (const float*)d_in[5];
    const float* w_cin   = (const float*)d_in[6];
    const float* w_k2    = (const float*)d_in[7];
    const float* w_out   = (const float*)d_in[8];
    float* y = (float*)d_out;

    float* ws      = (float*)d_ws;
    float* pooled  = ws;             // 4096
    float* cin_att = ws + 4096;      // 4096
    float* out_att = ws + 8192;      // 4096
    float* agg_b   = ws + 12288;     // 4096
    float* coef    = ws + 16384;     // 16*81 = 1296
    float* wsyn    = ws + 17680;     // 16*256*9*256 = 9,437,184 floats (~37.7 MB)

    pool_kernel<<<BS * CIN, 256, 0, stream>>>(x, pooled);
    attn_kernel<<<BS, 256, 0, stream>>>(pooled, b_base, b_extra, w_net, w_nfc,
                                        w_cin, w_k2, w_out,
                                        cin_att, out_att, agg_b, coef);
    wsyn_kernel<<<CIN, 256, 0, stream>>>(w_base, cin_att, out_att, coef, wsyn);
    conv_kernel<<<dim3(50, 4, BS), 256, 0, stream>>>(x, wsyn, agg_b, y);
}

// Round 4
// 358.731 us; speedup vs baseline: 4.6925x; 4.6925x over previous
//
#include <hip/hip_runtime.h>
#include <hip/hip_bf16.h>
#include <cstdint>
#include <cstddef>

// Problem constants
#define BS   16
#define CIN  256
#define COUT 256
#define HID  16
#define KNUM 5
#define TEMP 30.0f
#define NPIX 6400   // 80*80

typedef _Float16 half8 __attribute__((ext_vector_type(8)));
typedef float    f32x4 __attribute__((ext_vector_type(4)));

// direct global->LDS async copy, 16B per lane. LDS dest must be wave-uniform
// (HW adds lane*16); global addr is per-lane.
__device__ __forceinline__ void gload_lds16(const void* g, void* l) {
    __builtin_amdgcn_global_load_lds(
        (const __attribute__((address_space(1))) unsigned int*)g,
        (__attribute__((address_space(3))) unsigned int*)l, 16, 0, 0);
}

// ---------------------------------------------------------------------------
// zero pooled accumulator (ws is poisoned 0xAA before every timed launch)
// ---------------------------------------------------------------------------
__global__ void zero_pool_kernel(float* __restrict__ pooled) {
    pooled[blockIdx.x * 256 + threadIdx.x] = 0.f;
}

// ---------------------------------------------------------------------------
// x transpose + fused global-avg-pool partial sums.
// x[b][c][6400] fp32  ->  xt[b][pix][c] f16 ; pooled[b][c] += partial sum
// grid (100, 16): 64 pixels per block, thread = channel.
// ---------------------------------------------------------------------------
__global__ __launch_bounds__(256)
void xpose_kernel(const float* __restrict__ x, _Float16* __restrict__ xt,
                  float* __restrict__ pooled) {
    const int b = blockIdx.y, p0 = blockIdx.x * 64, c = threadIdx.x;
    const float* xp = x + ((size_t)(b * CIN + c)) * NPIX + p0;
    _Float16* tp = xt + ((size_t)b * NPIX + p0) * CIN + c;
    float s = 0.f;
    #pragma unroll
    for (int k0 = 0; k0 < 64; k0 += 16) {
        float4 v[4];
        #pragma unroll
        for (int q = 0; q < 4; ++q) v[q] = *(const float4*)(xp + k0 + q * 4);
        #pragma unroll
        for (int q = 0; q < 4; ++q) {
            s += v[q].x + v[q].y + v[q].z + v[q].w;
            tp[(size_t)(k0 + q * 4 + 0) * CIN] = (_Float16)v[q].x;
            tp[(size_t)(k0 + q * 4 + 1) * CIN] = (_Float16)v[q].y;
            tp[(size_t)(k0 + q * 4 + 2) * CIN] = (_Float16)v[q].z;
            tp[(size_t)(k0 + q * 4 + 3) * CIN] = (_Float16)v[q].w;
        }
    }
    atomicAdd(&pooled[b * CIN + c], s);
}

// ---------------------------------------------------------------------------
// attention head (per sample). pooled holds SUM (new path, scale=1/NPIX) or
// MEAN (old path, scale=1). Produces cin_att/out_att/agg_b/coef.
//   coef[b][d][s] = k2_att[d] * sum_k n_att[k]*[P_k[d]==s]
// ---------------------------------------------------------------------------
__global__ void attn_kernel(const float* __restrict__ pooled,
                            const float* __restrict__ b_base,
                            const float* __restrict__ b_extra,
                            const float* __restrict__ w_net,
                            const float* __restrict__ w_nfc,
                            const float* __restrict__ w_cin,
                            const float* __restrict__ w_k2,
                            const float* __restrict__ w_out,
                            float* __restrict__ cin_att,
                            float* __restrict__ out_att,
                            float* __restrict__ agg_b,
                            float* __restrict__ coef,
                            float pool_scale) {
    const int b = blockIdx.x;
    const int t = threadIdx.x;
    __shared__ float sp[CIN];
    __shared__ float sh[HID];
    __shared__ float sn[KNUM];
    __shared__ float sk2[9];

    sp[t] = pooled[b * CIN + t] * pool_scale;
    __syncthreads();

    if (t < HID) {
        float a = 0.f;
        for (int c = 0; c < CIN; ++c) a += sp[c] * w_net[t * CIN + c];
        sh[t] = fmaxf(a, 0.f);
    }
    __syncthreads();

    if (t == 0) {
        float l[KNUM], m = -1e30f;
        for (int k = 0; k < KNUM; ++k) {
            float a = 0.f;
            for (int j = 0; j < HID; ++j) a += sh[j] * w_nfc[k * HID + j];
            l[k] = a / TEMP;
            m = fmaxf(m, l[k]);
        }
        float ssum = 0.f;
        for (int k = 0; k < KNUM; ++k) { l[k] = __expf(l[k] - m); ssum += l[k]; }
        for (int k = 0; k < KNUM; ++k) sn[k] = l[k] / ssum;
    }
    if (t < 9) {
        float a = 0.f;
        for (int j = 0; j < HID; ++j) a += sh[j] * w_k2[t * HID + j];
        sk2[t] = 1.f / (1.f + __expf(-a));
    }
    __syncthreads();

    {
        float a = 0.f, o = 0.f;
        for (int j = 0; j < HID; ++j) {
            a += sh[j] * w_cin[t * HID + j];
            o += sh[j] * w_out[t * HID + j];
        }
        cin_att[b * CIN + t] = 1.f / (1.f + __expf(-a));
        out_att[b * COUT + t] = 1.f / (1.f + __expf(-o));
        float bb = sn[0] * b_base[t];
        for (int k = 1; k < KNUM; ++k) bb += sn[k] * b_extra[(k - 1) * COUT + t];
        agg_b[b * COUT + t] = bb;
    }

    if (t < 81) {
        const int P45[9]  = {3, 0, 1, 6, 4, 2, 7, 8, 5};
        const int P90[9]  = {6, 3, 0, 7, 4, 1, 8, 5, 2};
        const int P135[9] = {7, 6, 3, 8, 4, 0, 5, 2, 1};
        const int P180[9] = {8, 7, 6, 5, 4, 3, 2, 1, 0};
        const int d = t / 9, s = t % 9;
        float c = 0.f;
        if (d == s)        c += sn[0];
        if (P45[d]  == s)  c += sn[1];
        if (P90[d]  == s)  c += sn[2];
        if (P135[d] == s)  c += sn[3];
        if (P180[d] == s)  c += sn[4];
        coef[b * 81 + t] = c * sk2[d];
    }
}

// ---------------------------------------------------------------------------
// Weight synthesis, f16, pre-packed in MFMA A-fragment order:
//   wsyn[b][icb(8)][tap(9)][kb(4)][o(256)][j(8)]   (half)
//   value = out_att[b][o]*cin_att[b][i]*sum_s coef[b][tap][s]*w_base[o][i][s]
//   with i = icb*32 + kb*8 + j.
// grid (8 icb, 4 og, 16 b), 256 threads: t -> (kb = t>>6, o_l = t&63).
// ---------------------------------------------------------------------------
__global__ __launch_bounds__(256)
void wsyn_f16_kernel(const float* __restrict__ w_base,
                     const float* __restrict__ cin_att,
                     const float* __restrict__ out_att,
                     const float* __restrict__ coef,
                     _Float16* __restrict__ wsyn) {
    const int icb = blockIdx.x, og = blockIdx.y, b = blockIdx.z;
    const int t = threadIdx.x;
    const int kb = t >> 6, o_l = t & 63;
    const int o = og * 64 + o_l;
    const int i0 = icb * 32 + kb * 8;

    __shared__ float sc[81];
    if (t < 81) sc[t] = coef[b * 81 + t];
    __syncthreads();

    const float so = out_att[b * COUT + o];
    float wb[8][9], sci[8];
    const float* wp = w_base + ((size_t)o * CIN + i0) * 9;
    #pragma unroll
    for (int j = 0; j < 8; ++j) {
        sci[j] = cin_att[b * CIN + i0 + j] * so;
        #pragma unroll
        for (int s = 0; s < 9; ++s) wb[j][s] = wp[j * 9 + s];
    }
    #pragma unroll
    for (int tap = 0; tap < 9; ++tap) {
        half8 h;
        #pragma unroll
        for (int j = 0; j < 8; ++j) {
            float a = 0.f;
            #pragma unroll
            for (int s = 0; s < 9; ++s) a = fmaf(sc[tap * 9 + s], wb[j][s], a);
            h[j] = (_Float16)(a * sci[j]);
        }
        *(half8*)(wsyn + ((size_t)(b * 8 + icb) * 36 + tap * 4 + kb) * 2048
                        + (size_t)o * 8) = h;
    }
}

// ---------------------------------------------------------------------------
// MFMA implicit-GEMM conv. Block: 64 o x 256 px (16x16 spatial), one sample.
// 4 waves; wave w owns pixel rows 4w..4w+3 (64 px), all 64 o.
// K loop: 8 steps of 32 input channels; per step, 9 taps x 16 mfma/wave.
// LDS: W 36 KB (A-frag order, conflict-free) + x halo 18x18x(32+8pad) f16.
// ---------------------------------------------------------------------------
__global__ __launch_bounds__(256, 2)
void conv_mfma_kernel(const _Float16* __restrict__ xt,
                      const _Float16* __restrict__ wsyn,
                      const float* __restrict__ agg_b,
                      float* __restrict__ y) {
    const int tile = blockIdx.x;          // 0..24
    const int tc = tile % 5, tr = tile / 5;
    const int og = blockIdx.y;
    const int b = blockIdx.z;

    __shared__ _Float16 wlds[18432];      // [(tap*4+kb)][64 o][8]  = 36 KB
    __shared__ _Float16 xlds[12960];      // [(rr*18+cc)] x 40 (32+8 pad) = 25.9 KB

    const int t = threadIdx.x;
    const int w = t >> 6, lane = t & 63, l15 = lane & 15, l4 = lane >> 4;
    const int row0 = tr * 16 - 1, col0 = tc * 16 - 1;

    f32x4 acc[4][4];
    const f32x4 z = {0.f, 0.f, 0.f, 0.f};
    #pragma unroll
    for (int a = 0; a < 4; ++a)
        #pragma unroll
        for (int p = 0; p < 4; ++p) acc[a][p] = z;

    for (int icb = 0; icb < 8; ++icb) {
        // --- stage W: 36 KB linear copy via global_load_lds x16B ------------
        const _Float16* gw = wsyn + (size_t)(b * 8 + icb) * 73728 + og * 512;
        #pragma unroll
        for (int q = 0; q < 9; ++q) {
            const int L = q * 2048 + t * 8;        // half index in wlds
            const int tapkb = L >> 9;
            gload_lds16(gw + (size_t)tapkb * 2048 + (L & 511),
                        wlds + q * 2048 + w * 512);
        }
        // --- stage x halo: 18x18 pixels x 32 ic, row-padded to 80 B ---------
        const _Float16* gx = xt + (size_t)b * NPIX * CIN + icb * 32;
        #pragma unroll
        for (int it = 0; it < 6; ++it) {
            const int idx = t + it * 256;
            if (idx < 1296) {
                const int rc = idx >> 2, part = idx & 3;
                const int rr = rc / 18, cc = rc % 18;
                const int gr = row0 + rr, gc = col0 + cc;
                uint4 v = make_uint4(0u, 0u, 0u, 0u);
                if ((unsigned)gr < 80u && (unsigned)gc < 80u)
                    v = *(const uint4*)(gx + (size_t)(gr * 80 + gc) * CIN + part * 8);
                *(uint4*)((char*)xlds + rc * 80 + part * 16) = v;
            }
        }
        __syncthreads();

        // --- compute: per tap, A frags (4 o-tiles) x B frags (4 px rows) ----
        #pragma unroll
        for (int tap = 0; tap < 9; ++tap) {
            const int dh = tap / 3, dw = tap % 3;
            half8 A[4], Bv[4];
            #pragma unroll
            for (int ot = 0; ot < 4; ++ot)
                A[ot] = *(const half8*)(wlds +
                        ((size_t)(tap * 4 + l4) * 64 + ot * 16 + l15) * 8);
            #pragma unroll
            for (int pt = 0; pt < 4; ++pt)
                Bv[pt] = *(const half8*)((const char*)xlds +
                        ((w * 4 + pt + dh) * 18 + l15 + dw) * 80 + l4 * 16);
            #pragma unroll
            for (int ot = 0; ot < 4; ++ot)
                #pragma unroll
                for (int pt = 0; pt < 4; ++pt)
                    acc[ot][pt] = __builtin_amdgcn_mfma_f32_16x16x32_f16(
                        A[ot], Bv[pt], acc[ot][pt], 0, 0, 0);
        }
        __syncthreads();
    }

    // --- epilogue: bias + store (coalesced per 16-lane group) ---------------
    const int prow0 = tr * 16 + w * 4;
    #pragma unroll
    for (int ot = 0; ot < 4; ++ot) {
        const int o = og * 64 + ot * 16 + l4 * 4;
        #pragma unroll
        for (int q = 0; q < 4; ++q) {
            const float bv = agg_b[b * COUT + o + q];
            #pragma unroll
            for (int pt = 0; pt < 4; ++pt)
                y[(size_t)(b * COUT + o + q) * NPIX + (prow0 + pt) * 80
                  + tc * 16 + l15] = acc[ot][pt][q] + bv;
        }
    }
}

// ===========================================================================
// Fallback fp32 path (proven correct at 1683 us) — used only if ws too small.
// ===========================================================================
__global__ void pool_kernel(const float* __restrict__ x, float* __restrict__ pooled) {
    const int bc = blockIdx.x;
    const float* p = x + (size_t)bc * NPIX;
    float s = 0.f;
    for (int i = threadIdx.x; i < NPIX; i += 256) s += p[i];
    #pragma unroll
    for (int off = 32; off; off >>= 1) s += __shfl_down(s, off, 64);
    __shared__ float red[4];
    if ((threadIdx.x & 63) == 0) red[threadIdx.x >> 6] = s;
    __syncthreads();
    if (threadIdx.x == 0)
        pooled[bc] = (red[0] + red[1] + red[2] + red[3]) * (1.f / (float)NPIX);
}

__global__ void wsyn_kernel(const float* __restrict__ w_base,
                            const float* __restrict__ cin_att,
                            const float* __restrict__ out_att,
                            const float* __restrict__ coef,
                            float* __restrict__ wsyn) {
    const int i = blockIdx.x;
    const int o = threadIdx.x;
    __shared__ float sc[BS][81];
    __shared__ float sci[BS];
    for (int l = o; l < BS * 81; l += 256) sc[l / 81][l % 81] = coef[l];
    if (o < BS) sci[o] = cin_att[o * CIN + i];
    __syncthreads();

    float wb[9];
    const float* wp = w_base + ((size_t)o * CIN + i) * 9;
    #pragma unroll
    for (int s = 0; s < 9; ++s) wb[s] = wp[s];

    for (int b = 0; b < BS; ++b) {
        const float scale = sci[b] * out_att[b * COUT + o];
        float* outp = wsyn + (((size_t)b * CIN + i) * 9) * COUT + o;
        #pragma unroll
        for (int d = 0; d < 9; ++d) {
            float a = 0.f;
            #pragma unroll
            for (int s = 0; s < 9; ++s) a += sc[b][d * 9 + s] * wb[s];
            outp[(size_t)d * COUT] = a * scale;
        }
    }
}

__global__ __launch_bounds__(256, 3)
void conv_kernel(const float* __restrict__ x,
                 const float* __restrict__ wsyn,
                 const float* __restrict__ agg_b,
                 float* __restrict__ y) {
    const int tile = blockIdx.x;
    const int tx = tile % 5;
    const int ty = tile / 5;
    const int oBase = blockIdx.y * 64;
    const int b = blockIdx.z;

    __shared__ float xs[4][10][18];
    __shared__ float wsh[4][9][64];

    const int t  = threadIdx.x;
    const int og = t & 15;
    const int oL = og * 4;
    const int pg = t >> 4;
    const int r  = pg >> 1;
    const int c0 = (pg & 1) * 8;

    float acc[4][8];
    #pragma unroll
    for (int a = 0; a < 4; ++a)
        #pragma unroll
        for (int p = 0; p < 8; ++p) acc[a][p] = 0.f;

    const int row0 = ty * 8 - 1;
    const int col0 = tx * 16 - 1;
    const float* xb  = x + (size_t)b * CIN * NPIX;
    const float* wsb = wsyn + (size_t)b * CIN * 9 * COUT + oBase;

    for (int icb = 0; icb < CIN / 4; ++icb) {
        #pragma unroll
        for (int q = 0; q < 3; ++q) {
            const int l = t + q * 256;
            if (l < 720) {
                const int ic  = l / 180;
                const int rem = l % 180;
                const int rr  = rem / 18;
                const int cc  = rem % 18;
                const int gr = row0 + rr, gc = col0 + cc;
                float v = 0.f;
                if ((unsigned)gr < 80u && (unsigned)gc < 80u)
                    v = xb[(size_t)(icb * 4 + ic) * NPIX + gr * 80 + gc];
                ((float*)xs)[l] = v;
            }
        }
        #pragma unroll
        for (int q = 0; q < 9; ++q) {
            const int l = t + q * 256;
            const int ic  = l / 576;
            const int rem = l % 576;
            const int tap = rem / 64;
            const int o   = rem & 63;
            ((float*)wsh)[l] = wsb[(size_t)(icb * 4 + ic) * 9 * COUT + tap * COUT + o];
        }
        __syncthreads();

        #pragma unroll
        for (int ic = 0; ic < 4; ++ic) {
            float xr[3][10];
            #pragma unroll
            for (int dh = 0; dh < 3; ++dh)
                #pragma unroll
                for (int c = 0; c < 10; ++c) xr[dh][c] = xs[ic][r + dh][c0 + c];
            #pragma unroll
            for (int tap = 0; tap < 9; ++tap) {
                const int dh = tap / 3, dw = tap % 3;
                const float4 wv = *(const float4*)&wsh[ic][tap][oL];
                #pragma unroll
                for (int oo = 0; oo < 4; ++oo) {
                    const float wq = (&wv.x)[oo];
                    #pragma unroll
                    for (int p = 0; p < 8; ++p)
                        acc[oo][p] = fmaf(wq, xr[dh][p + dw], acc[oo][p]);
                }
            }
        }
        __syncthreads();
    }

    #pragma unroll
    for (int oo = 0; oo < 4; ++oo) {
        const int o = oBase + oL + oo;
        const float bv = agg_b[b * COUT + o];
        float* yp = y + (size_t)(b * COUT + o) * NPIX + (ty * 8 + r) * 80 + tx * 16 + c0;
        float4 v0 = make_float4(acc[oo][0] + bv, acc[oo][1] + bv,
                                acc[oo][2] + bv, acc[oo][3] + bv);
        float4 v1 = make_float4(acc[oo][4] + bv, acc[oo][5] + bv,
                                acc[oo][6] + bv, acc[oo][7] + bv);
        *(float4*)yp = v0;
        *((float4*)yp + 1) = v1;
    }
}

// ---------------------------------------------------------------------------
extern "C" void kernel_launch(void* const* d_in, const int* in_sizes, int n_in,
                              void* d_out, int out_size, void* d_ws, size_t ws_size,
                              hipStream_t stream) {
    const float* x       = (const float*)d_in[0];
    const float* w_base  = (const float*)d_in[1];
    const float* b_base  = (const float*)d_in[2];
    const float* b_extra = (const float*)d_in[3];
    const float* w_net   = (const float*)d_in[4];
    const float* w_nfc   = (const float*)d_in[5];
    const float* w_cin   = (const float*)d_in[6];
    const float* w_k2    = (const float*)d_in[7];
    const float* w_out   = (const float*)d_in[8];
    float* y = (float*)d_out;

    float* ws      = (float*)d_ws;
    float* pooled  = ws;
    float* cin_att = ws + 4096;
    float* out_att = ws + 8192;
    float* agg_b   = ws + 12288;
    float* coef    = ws + 16384;

    const size_t XT_OFF = 131072;                       // bytes
    const size_t WH_OFF = XT_OFF + (size_t)BS * NPIX * CIN * 2;   // + 52.4 MB
    const size_t NEED   = WH_OFF + (size_t)BS * 8 * 36 * 2048 * 2; // + 18.9 MB

    if (ws_size >= NEED) {
        _Float16* xt  = (_Float16*)((char*)d_ws + XT_OFF);
        _Float16* wh  = (_Float16*)((char*)d_ws + WH_OFF);
        zero_pool_kernel<<<BS, 256, 0, stream>>>(pooled);
        xpose_kernel<<<dim3(100, BS), 256, 0, stream>>>(x, xt, pooled);
        attn_kernel<<<BS, 256, 0, stream>>>(pooled, b_base, b_extra, w_net, w_nfc,
                                            w_cin, w_k2, w_out,
                                            cin_att, out_att, agg_b, coef,
                                            1.f / (float)NPIX);
        wsyn_f16_kernel<<<dim3(8, 4, BS), 256, 0, stream>>>(w_base, cin_att,
                                                            out_att, coef, wh);
        conv_mfma_kernel<<<dim3(25, 4, BS), 256, 0, stream>>>(xt, wh, agg_b, y);
    } else {
        float* wsyn = ws + 17680;
        pool_kernel<<<BS * CIN, 256, 0, stream>>>(x, pooled);
        attn_kernel<<<BS, 256, 0, stream>>>(pooled, b_base, b_extra, w_net, w_nfc,
                                            w_cin, w_k2, w_out,
                                            cin_att, out_att, agg_b, coef, 1.f);
        wsyn_kernel<<<CIN, 256, 0, stream>>>(w_base, cin_att, out_att, coef, wsyn);
        conv_kernel<<<dim3(50, 4, BS), 256, 0, stream>>>(x, wsyn, agg_b, y);
    }
}